// Round 4
// baseline (784.674 us; speedup 1.0000x reference)
//
#include <hip/hip_runtime.h>
#include <math.h>

typedef unsigned short u16;
typedef unsigned int   u32;
typedef u16   u16x8 __attribute__((ext_vector_type(8)));
typedef u16   u16x4 __attribute__((ext_vector_type(4)));
typedef u16   u16x2 __attribute__((ext_vector_type(2)));
typedef __bf16 bf16x8 __attribute__((ext_vector_type(8)));
typedef float  f32x4 __attribute__((ext_vector_type(4)));

__device__ __forceinline__ u16 f2b(float f) {
    union { float f; u32 u; } v; v.f = f;
    u32 u = v.u;
    return (u16)((u + 0x7FFFu + ((u >> 16) & 1u)) >> 16);
}

// async global->LDS, 16B per lane; LDS dest is wave-uniform base + lane*16
__device__ __forceinline__ void glds16(const void* g, void* l) {
    __builtin_amdgcn_global_load_lds(
        (__attribute__((address_space(1))) void*)(void*)g,
        (__attribute__((address_space(3))) void*)l, 16, 0, 0);
}

// ---------------------------------------------------------------------------
// f32 -> bf16 convert, same layout. 8 elems/thread.
// ---------------------------------------------------------------------------
__global__ __launch_bounds__(256) void convert_f32_bf16(
    const float* __restrict__ src, u16* __restrict__ dst)
{
    const size_t i = ((size_t)blockIdx.x * 256 + threadIdx.x) * 8;
    f32x4 a = *(const f32x4*)&src[i];
    f32x4 b = *(const f32x4*)&src[i + 4];
    u16x8 o;
    for (int j = 0; j < 4; ++j) { o[j] = f2b(a[j]); o[4 + j] = f2b(b[j]); }
    *(u16x8*)&dst[i] = o;
}

// ---------------------------------------------------------------------------
// f32 src (R x C) -> bf16 dst (C x R), 64x64 tiles, 256 threads
// ---------------------------------------------------------------------------
__global__ __launch_bounds__(256) void transpose_f32_bf16(
    const float* __restrict__ src, u16* __restrict__ dst, int R, int C)
{
    __shared__ u16 tile[64 * 72];
    const int t = threadIdx.x;
    const int r0 = blockIdx.y * 64, c0 = blockIdx.x * 64;
    for (int i = 0; i < 2; ++i) {
        int idx = i * 256 + t;
        int r = idx >> 3, c8 = (idx & 7) * 8;
        const float* sp = &src[(size_t)(r0 + r) * C + c0 + c8];
        f32x4 a = *(const f32x4*)sp;
        f32x4 b = *(const f32x4*)(sp + 4);
        u16x8 v;
        for (int j = 0; j < 4; ++j) { v[j] = f2b(a[j]); v[4 + j] = f2b(b[j]); }
        *(u16x8*)&tile[r * 72 + c8] = v;
    }
    __syncthreads();
    for (int i = 0; i < 2; ++i) {
        int idx = i * 256 + t;
        int orow = idx >> 3, oc8 = (idx & 7) * 8;
        u16x8 w;
        for (int j = 0; j < 8; ++j) w[j] = tile[(oc8 + j) * 72 + orow];
        *(u16x8*)&dst[(size_t)(c0 + orow) * R + r0 + oc8] = w;
    }
}

// ---------------------------------------------------------------------------
// RoPE in-place on (4096 x cols) bf16; pairs contiguous. fc: (2048,64,2) f32
// ---------------------------------------------------------------------------
__global__ __launch_bounds__(256) void rope_kernel(
    u16* __restrict__ x, const float* __restrict__ fc, int log2half, int cols)
{
    const int pid = blockIdx.x * 256 + threadIdx.x;
    const int row = pid >> log2half;
    const int pc  = pid & ((1 << log2half) - 1);
    const int l = row & 2047;
    const int p = pc & 63;
    const float c = fc[l * 128 + 2 * p];
    const float s = fc[l * 128 + 2 * p + 1];
    u16x2 v = *(u16x2*)&x[(size_t)row * cols + 2 * pc];
    union { u32 u; float f; } u0, u1;
    u0.u = ((u32)v[0]) << 16; u1.u = ((u32)v[1]) << 16;
    const float x0 = u0.f, x1 = u1.f;
    v[0] = f2b(x0 * c - x1 * s);
    v[1] = f2b(x0 * s + x1 * c);
    *(u16x2*)&x[(size_t)row * cols + 2 * pc] = v;
}

// ---------------------------------------------------------------------------
// BT-GEMM (m97 structure): A (4096 x 2048) bf16 @ Bt (N x 2048) bf16.
// MODE 0: cols [0,2048)->Q bf16 (ld 2048); [2048,3072)->K bf16 (ld 1024);
//         [3072,4096)->V TRANSPOSED bf16 into Vt[b*1024+kvh*128+d][l] (ld 2048)
// MODE 1: f32 out Fout (ld 2048).
// ---------------------------------------------------------------------------
template <int MODE>
__global__ __launch_bounds__(256) void gemm_bt(
    const u16* __restrict__ A, const u16* __restrict__ Bt,
    u16* __restrict__ D0, u16* __restrict__ D1, u16* __restrict__ D2,
    float* __restrict__ Fout)
{
    __shared__ u16 Alds[128 * 32];
    __shared__ u16 Blds[128 * 32];
    const int t = threadIdx.x;
    const int wid = t >> 6, lane = t & 63;
    const int l15 = lane & 15, qd = lane >> 4;
    const int row0 = blockIdx.y * 128, col0 = blockIdx.x * 128;
    const int wm = (wid >> 1) * 64, wn = (wid & 1) * 64;

    const int sm = lane >> 2;
    const int sk = (lane & 3) * 8;
    const int c0 = wid * 2;
    const u16* Ag0 = A  + (size_t)(row0 + c0 * 16 + sm) * 2048 + sk;
    const u16* Ag1 = A  + (size_t)(row0 + (c0 + 1) * 16 + sm) * 2048 + sk;
    const u16* Bg0 = Bt + (size_t)(col0 + c0 * 16 + sm) * 2048 + sk;
    const u16* Bg1 = Bt + (size_t)(col0 + (c0 + 1) * 16 + sm) * 2048 + sk;
    u16* Al0 = Alds + c0 * 512; u16* Al1 = Alds + (c0 + 1) * 512;
    u16* Bl0 = Blds + c0 * 512; u16* Bl1 = Blds + (c0 + 1) * 512;

    f32x4 acc[4][4] = {};

    for (int k0 = 0; k0 < 2048; k0 += 32) {
        glds16(Ag0 + k0, Al0);
        glds16(Ag1 + k0, Al1);
        glds16(Bg0 + k0, Bl0);
        glds16(Bg1 + k0, Bl1);
        __syncthreads();
        bf16x8 af[4], bfr[4];
        for (int mt = 0; mt < 4; ++mt)
            af[mt] = *(const bf16x8*)&Alds[(wm + mt * 16 + l15) * 32 + qd * 8];
        for (int nt = 0; nt < 4; ++nt)
            bfr[nt] = *(const bf16x8*)&Blds[(wn + nt * 16 + l15) * 32 + qd * 8];
        for (int mt = 0; mt < 4; ++mt)
            for (int nt = 0; nt < 4; ++nt)
                acc[mt][nt] = __builtin_amdgcn_mfma_f32_16x16x32_bf16(
                    af[mt], bfr[nt], acc[mt][nt], 0, 0, 0);
        __syncthreads();
    }

    for (int mt = 0; mt < 4; ++mt)
        for (int nt = 0; nt < 4; ++nt) {
            const int gcol = col0 + wn + nt * 16 + l15;
            const int grow0 = row0 + wm + mt * 16 + qd * 4;
            if (MODE == 1) {
                for (int r = 0; r < 4; ++r)
                    Fout[(size_t)(grow0 + r) * 2048 + gcol] = acc[mt][nt][r];
            } else if (gcol >= 3072) {
                const int vcol = gcol - 3072;
                const int vrow = vcol + (grow0 >> 11) * 1024;
                u16x4 v;
                for (int r = 0; r < 4; ++r) v[r] = f2b(acc[mt][nt][r]);
                *(u16x4*)&D2[(size_t)vrow * 2048 + (grow0 & 2047)] = v;
            } else {
                for (int r = 0; r < 4; ++r) {
                    const u16 v = f2b(acc[mt][nt][r]);
                    if (gcol < 2048)
                        D0[(size_t)(grow0 + r) * 2048 + gcol] = v;
                    else
                        D1[(size_t)(grow0 + r) * 1024 + (gcol - 2048)] = v;
                }
            }
        }
}

// ---------------------------------------------------------------------------
// Flash attention v2: block = 128 threads (2 waves), q-tile 64, K-tile 64.
// grid = (bh=32, qslot=32), qt = 31 - qslot (heavy first); bh in x -> all
// q-tiles of a (b,h) column share an XCD (KV stays in that XCD's L2).
// LDS 40KB: KS 16K (K-tile, swizzle ^(key&15)), VS 16K (Vt-tile, ^(d&7)),
// PS 8K (P, own-rows only -> no barrier around P). Register-prefetch of the
// next K/V tile overlaps global latency with compute.
// ---------------------------------------------------------------------------
__global__ __launch_bounds__(128, 2) void attn_kernel(
    const u16* __restrict__ Q, const u16* __restrict__ K,
    const u16* __restrict__ Vt, u16* __restrict__ AO)
{
    __shared__ u16 KS[64 * 128];   // 16KB: [key][d]
    __shared__ u16 VS[128 * 64];   // 16KB: [d][key]
    __shared__ u16 PS[64 * 64];    //  8KB: [q][key]
    const int t = threadIdx.x;
    const int w = t >> 6, lane = t & 63;
    const int l15 = lane & 15, qd = lane >> 4;
    const int bh = blockIdx.x;
    const int qt = 31 - (int)blockIdx.y;
    const int b = bh >> 4, h = bh & 15, kvh = h >> 1;
    const float SCL = 0.08838834764831845f * 1.4426950408889634f; // 1/sqrt(128)*log2e

    // Q fragments (A-layout) for this wave's 32 q rows
    bf16x8 qf[2][4];
    for (int mt = 0; mt < 2; ++mt) {
        const size_t grow = (size_t)b * 2048 + qt * 64 + w * 32 + mt * 16 + l15;
        const u16* qp = Q + grow * 2048 + h * 128 + qd * 8;
        for (int ks = 0; ks < 4; ++ks)
            qf[mt][ks] = *(const bf16x8*)(qp + ks * 32);
    }
    f32x4 Oa[2][8] = {};
    float mi[2][4], li[2][4];
    for (int mt = 0; mt < 2; ++mt)
        for (int r = 0; r < 4; ++r) { mi[mt][r] = -__builtin_inff(); li[mt][r] = 0.f; }

    const u16* Kbase = K  + (size_t)b * 2048 * 1024 + kvh * 128;   // +key*1024+d
    const u16* Vbase = Vt + (size_t)(b * 8 + kvh) * 128 * 2048;    // +d*2048+l

    // staging coords (per thread, fixed): K chunk c=i*128+t: key=c>>4, g=c&15
    //                                     V chunk: d=c>>3, g=c&7
    u16x8 kr[8], vr[8];
    #pragma unroll
    for (int i = 0; i < 8; ++i) {
        const int c = i * 128 + t;
        kr[i] = *(const u16x8*)(Kbase + (size_t)(c >> 4) * 1024 + (c & 15) * 8);
    }
    #pragma unroll
    for (int i = 0; i < 8; ++i) {
        const int c = i * 128 + t;
        vr[i] = *(const u16x8*)(Vbase + (size_t)(c >> 3) * 2048 + (c & 7) * 8);
    }

    for (int kt = 0; kt <= qt; ++kt) {
        __syncthreads();   // all waves done reading previous tile
        #pragma unroll
        for (int i = 0; i < 8; ++i) {
            const int c = i * 128 + t;
            const int key = c >> 4, g = c & 15;
            *(u16x8*)&KS[key * 128 + ((g ^ (key & 15)) << 3)] = kr[i];
        }
        #pragma unroll
        for (int i = 0; i < 8; ++i) {
            const int c = i * 128 + t;
            const int d = c >> 3, g = c & 7;
            *(u16x8*)&VS[d * 64 + ((g ^ (d & 7)) << 3)] = vr[i];
        }
        __syncthreads();
        if (kt < qt) {     // prefetch next tile (uniform branch)
            #pragma unroll
            for (int i = 0; i < 8; ++i) {
                const int c = i * 128 + t;
                kr[i] = *(const u16x8*)(Kbase +
                    (size_t)((kt + 1) * 64 + (c >> 4)) * 1024 + (c & 15) * 8);
            }
            #pragma unroll
            for (int i = 0; i < 8; ++i) {
                const int c = i * 128 + t;
                vr[i] = *(const u16x8*)(Vbase +
                    (size_t)(c >> 3) * 2048 + (kt + 1) * 64 + (c & 7) * 8);
            }
        }

        // S = Q @ K^T  (32 q x 64 keys per wave)
        f32x4 S[2][4] = {};
        for (int ks = 0; ks < 4; ++ks) {
            bf16x8 bk[4];
            for (int nt = 0; nt < 4; ++nt) {
                const int key = nt * 16 + l15;
                bk[nt] = *(const bf16x8*)&KS[key * 128 + (((ks * 4 + qd) ^ (key & 15)) << 3)];
            }
            for (int mt = 0; mt < 2; ++mt)
                for (int nt = 0; nt < 4; ++nt)
                    S[mt][nt] = __builtin_amdgcn_mfma_f32_16x16x32_bf16(
                        qf[mt][ks], bk[nt], S[mt][nt], 0, 0, 0);
        }
        if (kt == qt) {    // causal mask on diagonal tile
            for (int mt = 0; mt < 2; ++mt)
                for (int r = 0; r < 4; ++r) {
                    const int qg = w * 32 + mt * 16 + qd * 4 + r;
                    for (int nt = 0; nt < 4; ++nt)
                        if (nt * 16 + l15 > qg) S[mt][nt][r] = -__builtin_inff();
                }
        }
        // online softmax
        for (int mt = 0; mt < 2; ++mt)
            for (int r = 0; r < 4; ++r) {
                float rm = S[mt][0][r];
                for (int nt = 1; nt < 4; ++nt) rm = fmaxf(rm, S[mt][nt][r]);
                rm = fmaxf(rm, __shfl_xor(rm, 1));
                rm = fmaxf(rm, __shfl_xor(rm, 2));
                rm = fmaxf(rm, __shfl_xor(rm, 4));
                rm = fmaxf(rm, __shfl_xor(rm, 8));
                const float nm = fmaxf(mi[mt][r], rm);
                const float alpha = exp2f((mi[mt][r] - nm) * SCL);
                float rs = 0.f;
                for (int nt = 0; nt < 4; ++nt) {
                    const float p = exp2f((S[mt][nt][r] - nm) * SCL);
                    S[mt][nt][r] = p;
                    rs += p;
                }
                rs += __shfl_xor(rs, 1);
                rs += __shfl_xor(rs, 2);
                rs += __shfl_xor(rs, 4);
                rs += __shfl_xor(rs, 8);
                li[mt][r] = li[mt][r] * alpha + rs;
                mi[mt][r] = nm;
                for (int nt = 0; nt < 8; ++nt) Oa[mt][nt][r] *= alpha;
            }
        // P -> PS (own rows only; same-wave lgkmcnt ordering suffices)
        for (int mt = 0; mt < 2; ++mt)
            for (int nt = 0; nt < 4; ++nt)
                for (int r = 0; r < 4; ++r) {
                    const int qr = w * 32 + mt * 16 + qd * 4 + r;
                    const int key = nt * 16 + l15;
                    PS[qr * 64 + (((key >> 3) ^ (qr & 7)) << 3) + (key & 7)] =
                        f2b(S[mt][nt][r]);
                }
        // O += P @ V   (k-dim = 64 keys = 2 MFMA steps)
        for (int ks = 0; ks < 2; ++ks) {
            bf16x8 pa[2], vb[8];
            for (int mt = 0; mt < 2; ++mt) {
                const int qr = w * 32 + mt * 16 + l15;
                pa[mt] = *(const bf16x8*)&PS[qr * 64 + (((ks * 4 + qd) ^ (qr & 7)) << 3)];
            }
            for (int nt = 0; nt < 8; ++nt) {
                const int d = nt * 16 + l15;
                vb[nt] = *(const bf16x8*)&VS[d * 64 + (((ks * 4 + qd) ^ (d & 7)) << 3)];
            }
            for (int mt = 0; mt < 2; ++mt)
                for (int nt = 0; nt < 8; ++nt)
                    Oa[mt][nt] = __builtin_amdgcn_mfma_f32_16x16x32_bf16(
                        pa[mt], vb[nt], Oa[mt][nt], 0, 0, 0);
        }
    }

    // epilogue: normalize, round-trip through KS, coalesced 16B stores
    __syncthreads();
    for (int mt = 0; mt < 2; ++mt)
        for (int r = 0; r < 4; ++r) {
            const float inv = 1.f / li[mt][r];
            const int qr = w * 32 + mt * 16 + qd * 4 + r;
            for (int nt = 0; nt < 8; ++nt) {
                const int d = nt * 16 + l15;
                KS[qr * 128 + (((d >> 3) ^ (qr & 15)) << 3) + (d & 7)] =
                    f2b(Oa[mt][nt][r] * inv);
            }
        }
    __syncthreads();
    #pragma unroll
    for (int i = 0; i < 8; ++i) {
        const int c = i * 128 + t;
        const int row = c >> 4, g = c & 15;
        u16x8 v = *(const u16x8*)&KS[row * 128 + ((g ^ (row & 15)) << 3)];
        *(u16x8*)&AO[((size_t)b * 2048 + qt * 64 + row) * 2048 + h * 128 + g * 8] = v;
    }
}

// ---------------------------------------------------------------------------
extern "C" void kernel_launch(void* const* d_in, const int* in_sizes, int n_in,
                              void* d_out, int out_size, void* d_ws, size_t ws_size,
                              hipStream_t stream)
{
    (void)in_sizes; (void)n_in; (void)out_size; (void)ws_size;
    const float* x  = (const float*)d_in[0];
    const float* fc = (const float*)d_in[1];
    const float* wq = (const float*)d_in[2];
    const float* wk = (const float*)d_in[3];
    const float* wv = (const float*)d_in[4];
    const float* wo = (const float*)d_in[5];
    float* out = (float*)d_out;
    char* ws = (char*)d_ws;

    // workspace (72MB): AO overlays Xb (dead after gemm<0>)
    u16* Qb  = (u16*)(ws);                 // 16MB: 4096 x 2048 bf16
    u16* Kb  = (u16*)(ws + 16777216);      //  8MB: 4096 x 1024 bf16
    u16* Vt  = (u16*)(ws + 25165824);      //  8MB: [b*1024+kvh*128+d][l] bf16
    u16* Xb  = (u16*)(ws + 33554432);      // 16MB: 4096 x 2048 bf16
    u16* AO  = (u16*)(ws + 33554432);      // 16MB: overlays Xb
    u16* WT  = (u16*)(ws + 50331648);      // 16MB: 4096 x 2048 bf16 (wq|wk|wv)^T
    u16* WOT = (u16*)(ws + 67108864);      //  8MB: 2048 x 2048 bf16 wo^T

    convert_f32_bf16<<<4096, 256, 0, stream>>>(x, Xb);
    transpose_f32_bf16<<<dim3(32, 32), 256, 0, stream>>>(wq, WT, 2048, 2048);
    transpose_f32_bf16<<<dim3(16, 32), 256, 0, stream>>>(wk, WT + 2048 * 2048, 2048, 1024);
    transpose_f32_bf16<<<dim3(16, 32), 256, 0, stream>>>(wv, WT + 3072 * 2048, 2048, 1024);
    transpose_f32_bf16<<<dim3(32, 32), 256, 0, stream>>>(wo, WOT, 2048, 2048);

    gemm_bt<0><<<dim3(32, 32), 256, 0, stream>>>(Xb, WT, Qb, Kb, Vt, nullptr);

    rope_kernel<<<16384, 256, 0, stream>>>(Qb, fc, 10, 2048);
    rope_kernel<<<8192, 256, 0, stream>>>(Kb, fc, 9, 1024);

    attn_kernel<<<dim3(32, 32), 128, 0, stream>>>(Qb, Kb, Vt, AO);

    gemm_bt<1><<<dim3(16, 32), 256, 0, stream>>>(AO, WOT, nullptr, nullptr, nullptr, out);
}

// Round 5
// 428.006 us; speedup vs baseline: 1.8333x; 1.8333x over previous
//
#include <hip/hip_runtime.h>
#include <math.h>

typedef unsigned short u16;
typedef unsigned int   u32;
typedef u16   u16x8 __attribute__((ext_vector_type(8)));
typedef u16   u16x4 __attribute__((ext_vector_type(4)));
typedef u16   u16x2 __attribute__((ext_vector_type(2)));
typedef __bf16 bf16x8 __attribute__((ext_vector_type(8)));
typedef float  f32x4 __attribute__((ext_vector_type(4)));

__device__ __forceinline__ u16 f2b(float f) {
    union { float f; u32 u; } v; v.f = f;
    u32 u = v.u;
    return (u16)((u + 0x7FFFu + ((u >> 16) & 1u)) >> 16);
}

// async global->LDS, 16B per lane; LDS dest is wave-uniform base + lane*16.
// Global address is per-lane (verified m97 pattern).
__device__ __forceinline__ void glds16(const void* g, void* l) {
    __builtin_amdgcn_global_load_lds(
        (__attribute__((address_space(1))) void*)(void*)g,
        (__attribute__((address_space(3))) void*)l, 16, 0, 0);
}

// ---------------------------------------------------------------------------
// f32 -> bf16 convert, same layout. 8 elems/thread.
// ---------------------------------------------------------------------------
__global__ __launch_bounds__(256) void convert_f32_bf16(
    const float* __restrict__ src, u16* __restrict__ dst)
{
    const size_t i = ((size_t)blockIdx.x * 256 + threadIdx.x) * 8;
    f32x4 a = *(const f32x4*)&src[i];
    f32x4 b = *(const f32x4*)&src[i + 4];
    u16x8 o;
    for (int j = 0; j < 4; ++j) { o[j] = f2b(a[j]); o[4 + j] = f2b(b[j]); }
    *(u16x8*)&dst[i] = o;
}

// ---------------------------------------------------------------------------
// f32 src (R x C) -> bf16 dst (C x R), 64x64 tiles, 256 threads
// ---------------------------------------------------------------------------
__global__ __launch_bounds__(256) void transpose_f32_bf16(
    const float* __restrict__ src, u16* __restrict__ dst, int R, int C)
{
    __shared__ u16 tile[64 * 72];
    const int t = threadIdx.x;
    const int r0 = blockIdx.y * 64, c0 = blockIdx.x * 64;
    for (int i = 0; i < 2; ++i) {
        int idx = i * 256 + t;
        int r = idx >> 3, c8 = (idx & 7) * 8;
        const float* sp = &src[(size_t)(r0 + r) * C + c0 + c8];
        f32x4 a = *(const f32x4*)sp;
        f32x4 b = *(const f32x4*)(sp + 4);
        u16x8 v;
        for (int j = 0; j < 4; ++j) { v[j] = f2b(a[j]); v[4 + j] = f2b(b[j]); }
        *(u16x8*)&tile[r * 72 + c8] = v;
    }
    __syncthreads();
    for (int i = 0; i < 2; ++i) {
        int idx = i * 256 + t;
        int orow = idx >> 3, oc8 = (idx & 7) * 8;
        u16x8 w;
        for (int j = 0; j < 8; ++j) w[j] = tile[(oc8 + j) * 72 + orow];
        *(u16x8*)&dst[(size_t)(c0 + orow) * R + r0 + oc8] = w;
    }
}

// ---------------------------------------------------------------------------
// RoPE in-place on (4096 x cols) bf16; pairs contiguous. fc: (2048,64,2) f32
// ---------------------------------------------------------------------------
__global__ __launch_bounds__(256) void rope_kernel(
    u16* __restrict__ x, const float* __restrict__ fc, int log2half, int cols)
{
    const int pid = blockIdx.x * 256 + threadIdx.x;
    const int row = pid >> log2half;
    const int pc  = pid & ((1 << log2half) - 1);
    const int l = row & 2047;
    const int p = pc & 63;
    const float c = fc[l * 128 + 2 * p];
    const float s = fc[l * 128 + 2 * p + 1];
    u16x2 v = *(u16x2*)&x[(size_t)row * cols + 2 * pc];
    union { u32 u; float f; } u0, u1;
    u0.u = ((u32)v[0]) << 16; u1.u = ((u32)v[1]) << 16;
    const float x0 = u0.f, x1 = u1.f;
    v[0] = f2b(x0 * c - x1 * s);
    v[1] = f2b(x0 * s + x1 * c);
    *(u16x2*)&x[(size_t)row * cols + 2 * pc] = v;
}

// ---------------------------------------------------------------------------
// BT-GEMM (m97 structure): A (4096 x 2048) bf16 @ Bt (N x 2048) bf16.
// MODE 0: cols [0,2048)->Q bf16 (ld 2048); [2048,3072)->K bf16 (ld 1024);
//         [3072,4096)->V TRANSPOSED bf16 into Vt[b*1024+kvh*128+d][l] (ld 2048)
// MODE 1: f32 out Fout (ld 2048).
// ---------------------------------------------------------------------------
template <int MODE>
__global__ __launch_bounds__(256) void gemm_bt(
    const u16* __restrict__ A, const u16* __restrict__ Bt,
    u16* __restrict__ D0, u16* __restrict__ D1, u16* __restrict__ D2,
    float* __restrict__ Fout)
{
    __shared__ u16 Alds[128 * 32];
    __shared__ u16 Blds[128 * 32];
    const int t = threadIdx.x;
    const int wid = t >> 6, lane = t & 63;
    const int l15 = lane & 15, qd = lane >> 4;
    const int row0 = blockIdx.y * 128, col0 = blockIdx.x * 128;
    const int wm = (wid >> 1) * 64, wn = (wid & 1) * 64;

    const int sm = lane >> 2;
    const int sk = (lane & 3) * 8;
    const int c0 = wid * 2;
    const u16* Ag0 = A  + (size_t)(row0 + c0 * 16 + sm) * 2048 + sk;
    const u16* Ag1 = A  + (size_t)(row0 + (c0 + 1) * 16 + sm) * 2048 + sk;
    const u16* Bg0 = Bt + (size_t)(col0 + c0 * 16 + sm) * 2048 + sk;
    const u16* Bg1 = Bt + (size_t)(col0 + (c0 + 1) * 16 + sm) * 2048 + sk;
    u16* Al0 = Alds + c0 * 512; u16* Al1 = Alds + (c0 + 1) * 512;
    u16* Bl0 = Blds + c0 * 512; u16* Bl1 = Blds + (c0 + 1) * 512;

    f32x4 acc[4][4] = {};

    for (int k0 = 0; k0 < 2048; k0 += 32) {
        glds16(Ag0 + k0, Al0);
        glds16(Ag1 + k0, Al1);
        glds16(Bg0 + k0, Bl0);
        glds16(Bg1 + k0, Bl1);
        __syncthreads();
        bf16x8 af[4], bfr[4];
        for (int mt = 0; mt < 4; ++mt)
            af[mt] = *(const bf16x8*)&Alds[(wm + mt * 16 + l15) * 32 + qd * 8];
        for (int nt = 0; nt < 4; ++nt)
            bfr[nt] = *(const bf16x8*)&Blds[(wn + nt * 16 + l15) * 32 + qd * 8];
        for (int mt = 0; mt < 4; ++mt)
            for (int nt = 0; nt < 4; ++nt)
                acc[mt][nt] = __builtin_amdgcn_mfma_f32_16x16x32_bf16(
                    af[mt], bfr[nt], acc[mt][nt], 0, 0, 0);
        __syncthreads();
    }

    for (int mt = 0; mt < 4; ++mt)
        for (int nt = 0; nt < 4; ++nt) {
            const int gcol = col0 + wn + nt * 16 + l15;
            const int grow0 = row0 + wm + mt * 16 + qd * 4;
            if (MODE == 1) {
                for (int r = 0; r < 4; ++r)
                    Fout[(size_t)(grow0 + r) * 2048 + gcol] = acc[mt][nt][r];
            } else if (gcol >= 3072) {
                const int vcol = gcol - 3072;
                const int vrow = vcol + (grow0 >> 11) * 1024;
                u16x4 v;
                for (int r = 0; r < 4; ++r) v[r] = f2b(acc[mt][nt][r]);
                *(u16x4*)&D2[(size_t)vrow * 2048 + (grow0 & 2047)] = v;
            } else {
                for (int r = 0; r < 4; ++r) {
                    const u16 v = f2b(acc[mt][nt][r]);
                    if (gcol < 2048)
                        D0[(size_t)(grow0 + r) * 2048 + gcol] = v;
                    else
                        D1[(size_t)(grow0 + r) * 1024 + (gcol - 2048)] = v;
                }
            }
        }
}

// ---------------------------------------------------------------------------
// Flash attention v3: block = 256 thr (4 waves) handles (b, kvh, q-tile 64)
// for BOTH heads sharing kvh: wave w -> head kvh*2+(w>>1), q rows
// (w&1)*32+[0,32). grid = (b*8+kvh = 16, qslot = 32) -> each XCD owns 2 KV
// columns (2MB, L2-resident). K double-buffered via async glds16 (prefetch
// issued at iter start, drained by the vmcnt(0) the compiler emits at the
// mid-iter barrier); V single-buffered (staged at iter start, used after
// that barrier). LDS 64KB: K0|K1 (16K each) | V (16K) | P (4K/wave).
// All tiles land in LDS in MFMA-fragment order (lane->global inversion on
// the load side), so every hot ds_read_b128 is base+lane*16: conflict-free.
// ---------------------------------------------------------------------------
__global__ __launch_bounds__(256, 2) void attn_kernel(
    const u16* __restrict__ Q, const u16* __restrict__ K,
    const u16* __restrict__ Vt, u16* __restrict__ AO)
{
    __shared__ u16 SM[32768];          // 64KB
    const int t = threadIdx.x;
    const int w = t >> 6, lane = t & 63;
    const int l15 = lane & 15, qd = lane >> 4;
    const int b = blockIdx.x >> 3, kvh = blockIdx.x & 7;
    const int qt = 31 - (int)blockIdx.y;          // heavy tiles first
    const int h = kvh * 2 + (w >> 1);
    const float SCL = 0.08838834764831845f * 1.4426950408889634f; // 1/sqrt(128)*log2e

    u16* K0 = SM;                      // frag-ordered: frag*512 + lane*8 (u16)
    u16* K1 = SM + 8192;
    u16* VB = SM + 16384;
    u16* PW = SM + 24576 + w * 2048;   // wave-private P (32q x 64k)

    // Q fragments (A-layout): q rows = qt*64 + (w&1)*32 + mt*16 + l15
    bf16x8 qf[2][4];
    for (int mt = 0; mt < 2; ++mt) {
        const size_t grow = (size_t)b * 2048 + qt * 64 + (w & 1) * 32 + mt * 16 + l15;
        const u16* qp = Q + grow * 2048 + h * 128 + qd * 8;
        for (int ks = 0; ks < 4; ++ks)
            qf[mt][ks] = *(const bf16x8*)(qp + ks * 32);
    }
    f32x4 Oa[2][8] = {};
    float mi[2][4], li[2][4];
    for (int mt = 0; mt < 2; ++mt)
        for (int r = 0; r < 4; ++r) { mi[mt][r] = -__builtin_inff(); li[mt][r] = 0.f; }

    const u16* Kbase = K  + (size_t)b * 2048 * 1024 + kvh * 128;   // +key*1024+d
    const u16* Vbase = Vt + (size_t)(b * 8 + kvh) * 128 * 2048;    // +d*2048+l

    // prologue: stage K tile 0 (frag f: key=(f>>2)*16+l15, dchunk=(f&3)*4+qd)
    #pragma unroll
    for (int j = 0; j < 4; ++j) {
        const int f = w * 4 + j;
        glds16(Kbase + (size_t)((f >> 2) * 16 + l15) * 1024 + ((f & 3) * 4 + qd) * 8,
               K0 + f * 512);
    }
    __syncthreads();

    for (int kt = 0; kt <= qt; ++kt) {
        u16* Kc = (kt & 1) ? K1 : K0;
        u16* Kn = (kt & 1) ? K0 : K1;
        // issue async stages: K[kt+1] -> Kn, V[kt] -> VB
        if (kt < qt) {
            #pragma unroll
            for (int j = 0; j < 4; ++j) {
                const int f = w * 4 + j;
                glds16(Kbase + (size_t)((kt + 1) * 64 + (f >> 2) * 16 + l15) * 1024
                             + ((f & 3) * 4 + qd) * 8,
                       Kn + f * 512);
            }
        }
        #pragma unroll
        for (int j = 0; j < 4; ++j) {
            const int f = w * 4 + j;   // V frag: d=(f>>1)*16+l15, kchunk=(f&1)*4+qd
            glds16(Vbase + (size_t)((f >> 1) * 16 + l15) * 2048 + kt * 64
                         + ((f & 1) * 4 + qd) * 8,
                   VB + f * 512);
        }

        // S = Q @ K^T  (32 q x 64 keys per wave), reads conflict-free
        f32x4 S[2][4] = {};
        for (int ks = 0; ks < 4; ++ks) {
            bf16x8 bk[4];
            for (int nt = 0; nt < 4; ++nt)
                bk[nt] = *(const bf16x8*)&Kc[(nt * 4 + ks) * 512 + lane * 8];
            for (int mt = 0; mt < 2; ++mt)
                for (int nt = 0; nt < 4; ++nt)
                    S[mt][nt] = __builtin_amdgcn_mfma_f32_16x16x32_bf16(
                        qf[mt][ks], bk[nt], S[mt][nt], 0, 0, 0);
        }
        if (kt == qt) {   // causal mask on diagonal tile
            for (int mt = 0; mt < 2; ++mt)
                for (int r = 0; r < 4; ++r) {
                    const int qg = (w & 1) * 32 + mt * 16 + qd * 4 + r;
                    for (int nt = 0; nt < 4; ++nt)
                        if (nt * 16 + l15 > qg) S[mt][nt][r] = -__builtin_inff();
                }
        }
        // online softmax (rows replicated over the 16-lane col dim)
        for (int mt = 0; mt < 2; ++mt)
            for (int r = 0; r < 4; ++r) {
                float rm = S[mt][0][r];
                for (int nt = 1; nt < 4; ++nt) rm = fmaxf(rm, S[mt][nt][r]);
                rm = fmaxf(rm, __shfl_xor(rm, 1));
                rm = fmaxf(rm, __shfl_xor(rm, 2));
                rm = fmaxf(rm, __shfl_xor(rm, 4));
                rm = fmaxf(rm, __shfl_xor(rm, 8));
                const float nm = fmaxf(mi[mt][r], rm);
                const float alpha = exp2f((mi[mt][r] - nm) * SCL);
                float rs = 0.f;
                for (int nt = 0; nt < 4; ++nt) {
                    const float p = exp2f((S[mt][nt][r] - nm) * SCL);
                    S[mt][nt][r] = p;
                    rs += p;
                }
                rs += __shfl_xor(rs, 1);
                rs += __shfl_xor(rs, 2);
                rs += __shfl_xor(rs, 4);
                rs += __shfl_xor(rs, 8);
                li[mt][r] = li[mt][r] * alpha + rs;
                mi[mt][r] = nm;
                for (int nt = 0; nt < 8; ++nt) Oa[mt][nt][r] *= alpha;
            }
        // write P into wave-private A-frag-ordered LDS:
        // elem (q,key): addr = (mt*2+(nt>>1))*512 + ((nt*2+(l15>>3))&3)*128
        //               + (qd*4+r)*8 + (l15&7)
        for (int mt = 0; mt < 2; ++mt)
            for (int nt = 0; nt < 4; ++nt)
                for (int r = 0; r < 4; ++r)
                    PW[(mt * 2 + (nt >> 1)) * 512 + ((nt * 2 + (l15 >> 3)) & 3) * 128
                       + (qd * 4 + r) * 8 + (l15 & 7)] = f2b(S[mt][nt][r]);

        __syncthreads();   // drains vmcnt(0): Kn + VB loaded; publishes VB

        // O += P @ V  (reads conflict-free; P is own-wave)
        for (int ks = 0; ks < 2; ++ks) {
            bf16x8 pa[2], vb[8];
            for (int mt = 0; mt < 2; ++mt)
                pa[mt] = *(const bf16x8*)&PW[(mt * 2 + ks) * 512 + lane * 8];
            for (int nt = 0; nt < 8; ++nt)
                vb[nt] = *(const bf16x8*)&VB[(nt * 2 + ks) * 512 + lane * 8];
            for (int mt = 0; mt < 2; ++mt)
                for (int nt = 0; nt < 8; ++nt)
                    Oa[mt][nt] = __builtin_amdgcn_mfma_f32_16x16x32_bf16(
                        pa[mt], vb[nt], Oa[mt][nt], 0, 0, 0);
        }
        __syncthreads();   // all waves done reading VB (and Kc long done)
    }

    // epilogue: O block = 64 rows x 256 cols (both heads) via LDS (reuse K area)
    u16* OL = SM;          // 16384 u16 = 64 x 256
    for (int mt = 0; mt < 2; ++mt)
        for (int r = 0; r < 4; ++r) {
            const float inv = 1.f / li[mt][r];
            const int qr = (w & 1) * 32 + mt * 16 + qd * 4 + r;
            for (int nt = 0; nt < 8; ++nt)
                OL[qr * 256 + (w >> 1) * 128 + nt * 16 + l15] = f2b(Oa[mt][nt][r] * inv);
        }
    __syncthreads();
    #pragma unroll
    for (int i = 0; i < 8; ++i) {
        const int c = i * 256 + t;
        const int row = c >> 5, ch = c & 31;
        u16x8 v = *(const u16x8*)&OL[row * 256 + ch * 8];
        *(u16x8*)&AO[((size_t)b * 2048 + qt * 64 + row) * 2048 + kvh * 256 + ch * 8] = v;
    }
}

// ---------------------------------------------------------------------------
extern "C" void kernel_launch(void* const* d_in, const int* in_sizes, int n_in,
                              void* d_out, int out_size, void* d_ws, size_t ws_size,
                              hipStream_t stream)
{
    (void)in_sizes; (void)n_in; (void)out_size; (void)ws_size;
    const float* x  = (const float*)d_in[0];
    const float* fc = (const float*)d_in[1];
    const float* wq = (const float*)d_in[2];
    const float* wk = (const float*)d_in[3];
    const float* wv = (const float*)d_in[4];
    const float* wo = (const float*)d_in[5];
    float* out = (float*)d_out;
    char* ws = (char*)d_ws;

    // workspace (72MB): AO overlays Xb (dead after gemm<0>)
    u16* Qb  = (u16*)(ws);                 // 16MB: 4096 x 2048 bf16
    u16* Kb  = (u16*)(ws + 16777216);      //  8MB: 4096 x 1024 bf16
    u16* Vt  = (u16*)(ws + 25165824);      //  8MB: [b*1024+kvh*128+d][l] bf16
    u16* Xb  = (u16*)(ws + 33554432);      // 16MB: 4096 x 2048 bf16
    u16* AO  = (u16*)(ws + 33554432);      // 16MB: overlays Xb
    u16* WT  = (u16*)(ws + 50331648);      // 16MB: 4096 x 2048 bf16 (wq|wk|wv)^T
    u16* WOT = (u16*)(ws + 67108864);      //  8MB: 2048 x 2048 bf16 wo^T

    convert_f32_bf16<<<4096, 256, 0, stream>>>(x, Xb);
    transpose_f32_bf16<<<dim3(32, 32), 256, 0, stream>>>(wq, WT, 2048, 2048);
    transpose_f32_bf16<<<dim3(16, 32), 256, 0, stream>>>(wk, WT + 2048 * 2048, 2048, 1024);
    transpose_f32_bf16<<<dim3(16, 32), 256, 0, stream>>>(wv, WT + 3072 * 2048, 2048, 1024);
    transpose_f32_bf16<<<dim3(32, 32), 256, 0, stream>>>(wo, WOT, 2048, 2048);

    gemm_bt<0><<<dim3(32, 32), 256, 0, stream>>>(Xb, WT, Qb, Kb, Vt, nullptr);

    rope_kernel<<<16384, 256, 0, stream>>>(Qb, fc, 10, 2048);
    rope_kernel<<<8192, 256, 0, stream>>>(Kb, fc, 9, 1024);

    attn_kernel<<<dim3(16, 32), 256, 0, stream>>>(Qb, Kb, Vt, AO);

    gemm_bt<1><<<dim3(16, 32), 256, 0, stream>>>(AO, WOT, nullptr, nullptr, nullptr, out);
}